// Round 15
// baseline (271.213 us; speedup 1.0000x reference)
//
#include <hip/hip_runtime.h>

#define NSEQ  9216
#define CDIM  192
#define LOG2E 1.44269504088896f

typedef _Float16 h8_t  __attribute__((ext_vector_type(8)));
typedef _Float16 h4_t  __attribute__((ext_vector_type(4)));
typedef _Float16 h2_t  __attribute__((ext_vector_type(2)));
typedef __fp16   fp16x2 __attribute__((ext_vector_type(2)));
typedef float    f4_t  __attribute__((ext_vector_type(4)));
typedef float    f16v  __attribute__((ext_vector_type(16)));
typedef unsigned u32x2 __attribute__((ext_vector_type(2)));

static __device__ inline unsigned f2u(float f) { union { float f; unsigned u; } x; x.f = f; return x.u; }
static __device__ inline float u2f(unsigned u) { union { unsigned u; float f; } x; x.u = u; return x.f; }

// pack two f32 -> two f16 in one v_cvt_pkrtz_f16_f32
static __device__ inline unsigned cvt_pk(float a, float b) {
    union { fp16x2 h; unsigned u; } x;
    x.h = __builtin_amdgcn_cvt_pkrtz(a, b);
    return x.u;
}

// v_permlane32_swap_b32: r[0] = {a.lo, b.lo-from-partner}, r[1] = {a.hi-from-partner, b.hi}
static __device__ inline u32x2 plswap(unsigned a, unsigned b) {
    return __builtin_amdgcn_permlane32_swap(a, b, false, false);
}

// async global->LDS DMA, 16B per lane; LDS dest = wave-uniform base + lane*16
static __device__ inline void gl_lds16(const _Float16* g, _Float16* l) {
    __builtin_amdgcn_global_load_lds(
        (const __attribute__((address_space(1))) void*)g,
        (__attribute__((address_space(3))) void*)l,
        16, 0, 0);
}

// ---------------------------------------------------------------------------
// Kernel 0: Wq/Wk/Wv fp32 -> f16 Wh[3][192][192].  Wq pre-scaled by log2e.
// ---------------------------------------------------------------------------
__global__ __launch_bounds__(256) void wconv_kernel(
    const float* __restrict__ Wq, const float* __restrict__ Wk,
    const float* __restrict__ Wv, _Float16* __restrict__ Wh)
{
    int i = blockIdx.x * 256 + threadIdx.x;     // f4 index, 3*9216 total
    if (i >= 3 * 9216) return;
    const float* src = (i < 9216) ? Wq : (i < 18432 ? Wk : Wv);
    float s = (i < 9216) ? LOG2E : 1.f;
    int r = i % 9216;
    f4_t w = ((const f4_t*)src)[r];
    h4_t h = {(_Float16)(w[0]*s), (_Float16)(w[1]*s),
              (_Float16)(w[2]*s), (_Float16)(w[3]*s)};
    ((h4_t*)Wh)[i] = h;
}

// ---------------------------------------------------------------------------
// Kernel 0b: x[b][c][n] f32 -> xT[b][n][c] f16 (one block per (b, 32-n tile)).
//   Done ONCE so proj needs no LDS staging (it was re-staging x 3x, one per
//   matrix, with 48 scalar loads + cvts + LDS round-trip per block).
// ---------------------------------------------------------------------------
__global__ __launch_bounds__(256) void xconv_kernel(
    const float* __restrict__ x, _Float16* __restrict__ xT)
{
    __shared__ __align__(16) _Float16 Xs[32 * 200];   // [n][c], 200-hw stride

    const int tid = threadIdx.x;
    const int b   = blockIdx.x / 288;
    const int n0  = (blockIdx.x % 288) * 32;

    {
        const int nn = tid & 31;
        const int c0 = (tid >> 5) * 24;               // 8 groups of 24 c
        const float* xp = x + (size_t)(b * CDIM + c0) * NSEQ + n0 + nn;
        _Float16 tmp[24];
        #pragma unroll
        for (int j = 0; j < 24; j++)
            tmp[j] = (_Float16)xp[(size_t)j * NSEQ];
        #pragma unroll
        for (int g = 0; g < 6; g++) {
            h4_t h = {tmp[4*g], tmp[4*g+1], tmp[4*g+2], tmp[4*g+3]};
            *(h4_t*)(Xs + nn * 200 + c0 + 4 * g) = h;
        }
    }
    __syncthreads();

    // write 32 rows x 192 c = 768 h8 chunks, coalesced in c
    #pragma unroll
    for (int r = 0; r < 3; r++) {
        int i = r * 256 + tid;
        int row = i / 24, col = i % 24;
        h8_t h = *(const h8_t*)(Xs + row * 200 + col * 8);
        *(h8_t*)(xT + ((size_t)b * NSEQ + n0 + row) * CDIM + col * 8) = h;
    }
}

// ---------------------------------------------------------------------------
// Kernel 1: QKV projection, LDS-FREE.  One block = (b, n-tile, mat), 2 waves.
//   B-fragments load DIRECTLY from xT[b][n][c] (flash's Q-load pattern) --
//   no staging, no cvts, no barrier.  1728 blocks x 128 thr,
//   __launch_bounds__(128,4) -> 8 blocks/CU = 2048 slots -> single round.
// ---------------------------------------------------------------------------
__global__ __launch_bounds__(128, 4) void proj_kernel(
    const _Float16* __restrict__ xT, const _Float16* __restrict__ Wh,
    const float* __restrict__ bq, const float* __restrict__ bk,
    const float* __restrict__ bv,
    _Float16* __restrict__ QT, _Float16* __restrict__ KT, _Float16* __restrict__ Vg)
{
    const int tid  = threadIdx.x;                 // 0..127
    const int lane = tid & 63, wave = tid >> 6;   // wave 0..1
    const int L31  = lane & 31, hi = lane >> 5;
    const int bid  = blockIdx.x;                  // (b*288 + ntile)*3 + mat
    const int mat  = bid % 3;
    const int bt   = bid / 3;
    const int b    = bt / 288;
    const int n0   = (bt % 288) * 32;

    const int sh = wave * 3;             // wave 0: ch 0-95, wave 1: ch 96-191
    const int n  = n0 + L31;

    // B-fragments straight from global: B[k=c][col=n=L31]
    h8_t bf[12];
    const _Float16* xb = xT + ((size_t)b * NSEQ + n) * CDIM + hi * 8;
    #pragma unroll
    for (int t = 0; t < 12; t++) bf[t] = *(const h8_t*)(xb + t * 16);

    const _Float16* W = Wh + mat * CDIM * CDIM;
    const float* bias = (mat == 0) ? bq : (mat == 1 ? bk : bv);
    const float bscale = (mat == 0) ? LOG2E : 1.f;

    f16v acc[3];
    #pragma unroll
    for (int s = 0; s < 3; s++)
        #pragma unroll
        for (int r = 0; r < 16; r++) acc[s][r] = 0.f;

    #pragma unroll
    for (int t = 0; t < 12; t++) {
        #pragma unroll
        for (int s = 0; s < 3; s++) {
            h8_t a = *(const h8_t*)(W + ((sh + s) * 32 + L31) * CDIM + t * 16 + hi * 8);
            acc[s] = __builtin_amdgcn_mfma_f32_32x32x16_f16(a, bf[t], acc[s], 0, 0, 0);
        }
    }

    if (mat < 2) {
        _Float16* dst = ((mat == 0) ? QT : KT) + ((size_t)b * NSEQ + n) * CDIM;
        #pragma unroll
        for (int s = 0; s < 3; s++) {
            #pragma unroll
            for (int g = 0; g < 4; g++) {
                f4_t bb = *(const f4_t*)&bias[(sh + s) * 32 + 8 * g + 4 * hi];
                h4_t h = {(_Float16)(acc[s][4*g+0] + bb[0] * bscale),
                          (_Float16)(acc[s][4*g+1] + bb[1] * bscale),
                          (_Float16)(acc[s][4*g+2] + bb[2] * bscale),
                          (_Float16)(acc[s][4*g+3] + bb[3] * bscale)};
                *(h4_t*)(dst + (sh + s) * 32 + 8 * g + 4 * hi) = h;
            }
        }
    } else {
        #pragma unroll
        for (int s = 0; s < 3; s++) {
            #pragma unroll
            for (int g = 0; g < 4; g++) {
                f4_t bb = *(const f4_t*)&bias[(sh + s) * 32 + 8 * g + 4 * hi];
                #pragma unroll
                for (int r = 0; r < 4; r++) {
                    int o = (sh + s) * 32 + 8 * g + 4 * hi + r;
                    Vg[((size_t)b * CDIM + o) * NSEQ + n] =
                        (_Float16)(acc[s][4*g+r] + bb[r]);
                }
            }
        }
    }
}

// ---------------------------------------------------------------------------
// Kernel 2: flash attention (R9 exact -- best measured, ~165 us).
//   Full global_load_lds DMA staging, double-buffered K and V, ONE
//   __syncthreads per iter, source-side swizzle for conflict-free reads:
//   K chunk rotate (key&7) mod 24, V seg rotate (c>>1)&3.
//   K bufs at 0/12288, V bufs at 24576/36864.  NSPLIT=7 -> 1008 blocks
//   ~ 2 full rounds at 2 blocks/CU (98.4% slot efficiency).
//   Nulls (reverted): chain-split, counted-vmcnt triple-buf, T15 pipeline,
//   setprio, hybrid staging.
// ---------------------------------------------------------------------------
template<int NSPLIT>
__global__ __launch_bounds__(256, 2) void flash_kernel(
    const _Float16* __restrict__ QT, const _Float16* __restrict__ KTg,
    const _Float16* __restrict__ Vg,
    _Float16* __restrict__ O_part, float* __restrict__ m_part, float* __restrict__ l_part)
{
    constexpr int TKI  = NSEQ / 32;               // 288 total k-iters
    constexpr int base = TKI / NSPLIT, rem = TKI % NSPLIT;
    __shared__ __align__(16) _Float16 Sh[25600];  // 51,200 B

    const int tid  = threadIdx.x;
    const int lane = tid & 63, wave = tid >> 6;
    const int L31  = lane & 31, hi = lane >> 5;
    const int qtile = blockIdx.x, split = blockIdx.y, b = blockIdx.z;
    const int q0 = qtile * 128 + wave * 32;

    const int nk     = base + (split < rem ? 1 : 0);
    const int kstart = split * base + (split < rem ? split : rem);

    // resident Q B-fragments: B[k=c][col=q=L31]
    h8_t qf[12];
    const _Float16* qbase = QT + ((size_t)b * NSEQ + q0 + L31) * CDIM + hi * 8;
    #pragma unroll
    for (int t = 0; t < 12; t++) qf[t] = *(const h8_t*)(qbase + t * 16);

    f16v acc[6];
    #pragma unroll
    for (int s = 0; s < 6; s++)
        #pragma unroll
        for (int r = 0; r < 16; r++) acc[s][r] = 0.f;
    float m_run = -__builtin_inff();
    float l_run = 0.f;

    const _Float16* ksrc = KTg + ((size_t)b * NSEQ + kstart * 32) * CDIM;
    const _Float16* vsrc = Vg + (size_t)b * CDIM * NSEQ + kstart * 32;

    // ---- read-side offsets (loop-invariant, buffer chosen by imm) ----
    const int k7 = L31 & 7;
    int ka[12];                                   // byte offsets in K buffer
    #pragma unroll
    for (int t = 0; t < 12; t++) {
        int p = 2 * t + hi + k7; if (p >= 24) p -= 24;
        ka[t] = L31 * 384 + p * 16;
    }
    const int r2 = L31 >> 1;
    const int va0 = L31 * 64 + (((hi + r2) & 3) * 16);       // ks=0
    const int va1 = L31 * 64 + (((2 + hi + r2) & 3) * 16);   // ks=1

    // ---- stage-side per-lane global pointers (source-swizzled) ----
    const _Float16 *kp[3], *vp[3];
    #pragma unroll
    for (int r = 0; r < 3; r++) {
        int i = r * 256 + tid;                    // linear 16B-chunk index
        int row = i / 24, pp = i % 24;
        int c = pp - (row & 7); if (c < 0) c += 24;
        kp[r] = ksrc + row * CDIM + c * 8;
        int cv = i >> 2, s = i & 3;
        int g = (s - (cv >> 1)) & 3;
        vp[r] = vsrc + (size_t)cv * NSEQ + g * 8;
    }

    auto stage = [&](int kbB, int vbB) {          // DMA tile at kp/vp, advance
        #pragma unroll
        for (int r = 0; r < 3; r++) {
            int off = (r * 256 + wave * 64) * 16;
            gl_lds16(kp[r], (_Float16*)((char*)Sh + kbB + off));
            gl_lds16(vp[r], (_Float16*)((char*)Sh + vbB + off));
        }
        #pragma unroll
        for (int r = 0; r < 3; r++) { kp[r] += 32 * CDIM; vp[r] += 32; }
    };

    stage(0, 24576);                              // tile 0 -> buffer 0
    __syncthreads();                              // (drains vmcnt)

    auto body = [&](int kt, int KB, int VB, int KW, int VW) {
        if (kt + 1 < nk) stage(KW, VW);           // next tile -> other buffer

        // S^T[key][q]: A = K[key=L31][c] from K buf, B = qf
        f16v st;
        #pragma unroll
        for (int r = 0; r < 16; r++) st[r] = 0.f;
        #pragma unroll
        for (int t = 0; t < 12; t++) {
            h8_t a = *(const h8_t*)((char*)Sh + KB + ka[t]);
            st = __builtin_amdgcn_mfma_f32_32x32x16_f16(a, qf[t], st, 0, 0, 0);
        }

        // tile max tree, cross-half combine via permlane
        float a0 = fmaxf(fmaxf(st[0], st[1]),  st[2]);
        float a1 = fmaxf(fmaxf(st[3], st[4]),  st[5]);
        float a2 = fmaxf(fmaxf(st[6], st[7]),  st[8]);
        float a3 = fmaxf(fmaxf(st[9], st[10]), st[11]);
        float a4 = fmaxf(fmaxf(st[12], st[13]), st[14]);
        float mx = fmaxf(fmaxf(fmaxf(a0, a1), fmaxf(a2, a3)), fmaxf(a4, st[15]));
        u32x2 mxw = plswap(f2u(mx), f2u(mx));
        mx = fmaxf(u2f(mxw[0]), u2f(mxw[1]));

        // defer-max rescale (rare after iter 0)
        if (__builtin_expect(__any(mx > m_run + 9.f), 0)) {
            float m_new = fmaxf(m_run, mx);
            float alpha = __builtin_exp2f(m_run - m_new);
            l_run *= alpha;
            #pragma unroll
            for (int cs = 0; cs < 6; cs++)
                #pragma unroll
                for (int r = 0; r < 16; r++) acc[cs][r] *= alpha;
            m_run = m_new;
        }

        // P = exp2(S - m_run), pack f16 pairs
        unsigned pu[8];
        float ps0 = 0.f, ps1 = 0.f;
        #pragma unroll
        for (int t2 = 0; t2 < 8; t2++) {
            float e0 = __builtin_exp2f(st[2*t2]   - m_run);
            float e1 = __builtin_exp2f(st[2*t2+1] - m_run);
            ps0 += e0; ps1 += e1;
            pu[t2] = cvt_pk(e0, e1);
        }
        l_run += ps0 + ps1;

        // half-exchange via permlane32_swap
        union { h8_t h; unsigned u[4]; } pb0, pb1;
        u32x2 x0 = plswap(pu[0], pu[2]);
        u32x2 x1 = plswap(pu[1], pu[3]);
        u32x2 x2 = plswap(pu[4], pu[6]);
        u32x2 x3 = plswap(pu[5], pu[7]);
        pb0.u[0] = x0[0]; pb0.u[1] = x1[0]; pb0.u[2] = x0[1]; pb0.u[3] = x1[1];
        pb1.u[0] = x2[0]; pb1.u[1] = x3[0]; pb1.u[2] = x2[1]; pb1.u[3] = x3[1];

        // PV flipped: D[m=c][n=q] += V[c][key] * P^T[key][q]
        #pragma unroll
        for (int ks = 0; ks < 2; ks++) {
            h8_t pb = ks ? pb1.h : pb0.h;
            int vaof = ks ? va1 : va0;
            #pragma unroll
            for (int cs = 0; cs < 6; cs++) {
                h8_t va = *(const h8_t*)((char*)Sh + VB + cs * 2048 + vaof);
                acc[cs] = __builtin_amdgcn_mfma_f32_32x32x16_f16(va, pb, acc[cs], 0, 0, 0);
            }
        }

        __syncthreads();   // single convergence point (drains this wave's DMA)
    };

    int kt = 0;
    for (; kt + 1 < nk; kt += 2) {
        body(kt,     0,     24576, 12288, 36864);
        body(kt + 1, 12288, 36864, 0,     24576);
    }
    if (kt < nk)                                   // odd split size tail
        body(kt, 0, 24576, 12288, 36864);

    // epilogue
    u32x2 lw = plswap(f2u(l_run), f2u(l_run));
    float l_tot = u2f(lw[0]) + u2f(lw[1]);
    const size_t pw = (size_t)(b * NSPLIT + split) * NSEQ + q0;
    if (lane < 32) {
        m_part[pw + lane] = m_run;
        l_part[pw + lane] = l_tot;
    }
    // per-wave transpose through LDS (loop-end barrier separates last reads)
    _Float16* T = Sh + wave * 6400;
    #pragma unroll
    for (int cs = 0; cs < 6; cs++)
        #pragma unroll
        for (int g = 0; g < 4; g++) {
            h4_t hh = {(_Float16)acc[cs][4*g+0], (_Float16)acc[cs][4*g+1],
                       (_Float16)acc[cs][4*g+2], (_Float16)acc[cs][4*g+3]};
            *(h4_t*)(T + L31 * 200 + cs * 32 + 8 * g + 4 * hi) = hh;
        }
    _Float16* ob = O_part + pw * CDIM;
    #pragma unroll
    for (int it = 0; it < 12; it++) {
        int i = it * 64 + lane;
        int qq = i / 24, col = i % 24;
        h8_t h = *(const h8_t*)(T + qq * 200 + col * 8);
        *(h8_t*)(ob + (size_t)qq * CDIM + col * 8) = h;
    }
}

// ---------------------------------------------------------------------------
// Kernel 3: merge NS splits, normalize (log2 domain), transpose to out[b][c][n]
// ---------------------------------------------------------------------------
template<int NS>
__global__ __launch_bounds__(256) void combine_kernel(
    const _Float16* __restrict__ O_part, const float* __restrict__ m_part,
    const float* __restrict__ l_part, float* __restrict__ out)
{
    __shared__ float Cs[CDIM][33];
    __shared__ float winv[NS][32];
    const int tid = threadIdx.x;
    const int b  = blockIdx.y;
    const int n0 = blockIdx.x * 32;

    if (tid < 32) {
        int n = n0 + tid;
        float mm[NS], ll[NS], ms = -__builtin_inff();
        #pragma unroll
        for (int s = 0; s < NS; s++) {
            mm[s] = m_part[(b * NS + s) * NSEQ + n];
            ll[s] = l_part[(b * NS + s) * NSEQ + n];
            ms = fmaxf(ms, mm[s]);
        }
        float denom = 0.f;
        #pragma unroll
        for (int s = 0; s < NS; s++) {
            float w = __builtin_exp2f(mm[s] - ms);
            mm[s] = w;
            denom += w * ll[s];
        }
        #pragma unroll
        for (int s = 0; s < NS; s++) winv[s][tid] = mm[s] / denom;
    }
    __syncthreads();

    for (int i = tid; i < 32 * 24; i += 256) {
        int nl = i / 24, cp = i % 24;          // cp: group of 8 channels
        float v[8];
        #pragma unroll
        for (int j = 0; j < 8; j++) v[j] = 0.f;
        #pragma unroll
        for (int s = 0; s < NS; s++) {
            h8_t op = *(const h8_t*)(O_part +
                ((size_t)(b * NS + s) * NSEQ + n0 + nl) * CDIM + cp * 8);
            float w = winv[s][nl];
            #pragma unroll
            for (int j = 0; j < 8; j++) v[j] += w * (float)op[j];
        }
        #pragma unroll
        for (int j = 0; j < 8; j++) Cs[cp * 8 + j][nl] = v[j];
    }
    __syncthreads();
    for (int i = tid; i < CDIM * 32; i += 256) {
        int nl = i & 31, c = i >> 5;
        out[((size_t)b * CDIM + c) * NSEQ + n0 + nl] = Cs[c][nl];
    }
}

// ---------------------------------------------------------------------------
extern "C" void kernel_launch(void* const* d_in, const int* in_sizes, int n_in,
                              void* d_out, int out_size, void* d_ws, size_t ws_size,
                              hipStream_t stream)
{
    const float* x  = (const float*)d_in[0];
    const float* Wq = (const float*)d_in[1];
    const float* bq = (const float*)d_in[2];
    const float* Wk = (const float*)d_in[3];
    const float* bk = (const float*)d_in[4];
    const float* Wv = (const float*)d_in[5];
    const float* bv = (const float*)d_in[6];
    float* out = (float*)d_out;

    // workspace layout
    char* ws = (char*)d_ws;
    _Float16* QT = (_Float16*)(ws);                    // 7,077,888 B
    _Float16* KT = (_Float16*)(ws + 7077888);
    _Float16* Vg = (_Float16*)(ws + 14155776);
    char* tail = ws + 21233664;
    _Float16* Wh = (_Float16*)tail;                    // 221,184 B, aliases O_part
    // xT aliases O_part bytes [221184, 7299072): written by xconv, read by
    // proj (both BEFORE flash overwrites the region with O_part).
    _Float16* xT = (_Float16*)(tail + 221184);         // 7,077,888 B
    _Float16* O_part = (_Float16*)tail;                // NS * 7,077,888 B (f16)

    wconv_kernel<<<108, 256, 0, stream>>>(Wq, Wk, Wv, Wh);
    xconv_kernel<<<576, 256, 0, stream>>>(x, xT);
    proj_kernel<<<1728, 128, 0, stream>>>(xT, Wh, bq, bk, bv, QT, KT, Vg);

    const size_t need7 = 21233664ull + 7 * 7077888ull + 2 * 516096ull;  // 71,811,072
    const size_t need4 = 21233664ull + 4 * 7077888ull + 2 * 294912ull;  // 50,135,040
    if (ws_size >= need7) {
        float* m_part = (float*)(tail + 7 * 7077888ull);
        float* l_part = (float*)(tail + 7 * 7077888ull + 516096ull);
        flash_kernel<7><<<dim3(72, 7, 2), 256, 0, stream>>>(QT, KT, Vg, O_part, m_part, l_part);
        combine_kernel<7><<<dim3(288, 2), 256, 0, stream>>>(O_part, m_part, l_part, out);
    } else if (ws_size >= need4) {
        float* m_part = (float*)(tail + 4 * 7077888ull);
        float* l_part = (float*)(tail + 4 * 7077888ull + 294912ull);
        flash_kernel<4><<<dim3(72, 4, 2), 256, 0, stream>>>(QT, KT, Vg, O_part, m_part, l_part);
        combine_kernel<4><<<dim3(288, 2), 256, 0, stream>>>(O_part, m_part, l_part, out);
    } else {
        float* m_part = (float*)(tail + 2 * 7077888ull);
        float* l_part = (float*)(tail + 2 * 7077888ull + 147456ull);
        flash_kernel<2><<<dim3(72, 2, 2), 256, 0, stream>>>(QT, KT, Vg, O_part, m_part, l_part);
        combine_kernel<2><<<dim3(288, 2), 256, 0, stream>>>(O_part, m_part, l_part, out);
    }
}

// Round 16
// 261.416 us; speedup vs baseline: 1.0375x; 1.0375x over previous
//
#include <hip/hip_runtime.h>

#define NSEQ  9216
#define CDIM  192
#define LOG2E 1.44269504088896f

typedef _Float16 h8_t  __attribute__((ext_vector_type(8)));
typedef _Float16 h4_t  __attribute__((ext_vector_type(4)));
typedef _Float16 h2_t  __attribute__((ext_vector_type(2)));
typedef __fp16   fp16x2 __attribute__((ext_vector_type(2)));
typedef float    f4_t  __attribute__((ext_vector_type(4)));
typedef float    f16v  __attribute__((ext_vector_type(16)));
typedef unsigned u32x2 __attribute__((ext_vector_type(2)));

static __device__ inline unsigned f2u(float f) { union { float f; unsigned u; } x; x.f = f; return x.u; }
static __device__ inline float u2f(unsigned u) { union { unsigned u; float f; } x; x.u = u; return x.f; }

// pack two f32 -> two f16 in one v_cvt_pkrtz_f16_f32
static __device__ inline unsigned cvt_pk(float a, float b) {
    union { fp16x2 h; unsigned u; } x;
    x.h = __builtin_amdgcn_cvt_pkrtz(a, b);
    return x.u;
}

// v_permlane32_swap_b32: r[0] = {a.lo, b.lo-from-partner}, r[1] = {a.hi-from-partner, b.hi}
static __device__ inline u32x2 plswap(unsigned a, unsigned b) {
    return __builtin_amdgcn_permlane32_swap(a, b, false, false);
}

// async global->LDS DMA, 16B per lane; LDS dest = wave-uniform base + lane*16
static __device__ inline void gl_lds16(const _Float16* g, _Float16* l) {
    __builtin_amdgcn_global_load_lds(
        (const __attribute__((address_space(1))) void*)g,
        (__attribute__((address_space(3))) void*)l,
        16, 0, 0);
}

// ---------------------------------------------------------------------------
// Kernel 0: Wq/Wk/Wv fp32 -> f16 Wh[3][192][192].  Wq pre-scaled by log2e.
// ---------------------------------------------------------------------------
__global__ __launch_bounds__(256) void wconv_kernel(
    const float* __restrict__ Wq, const float* __restrict__ Wk,
    const float* __restrict__ Wv, _Float16* __restrict__ Wh)
{
    int i = blockIdx.x * 256 + threadIdx.x;     // f4 index, 3*9216 total
    if (i >= 3 * 9216) return;
    const float* src = (i < 9216) ? Wq : (i < 18432 ? Wk : Wv);
    float s = (i < 9216) ? LOG2E : 1.f;
    int r = i % 9216;
    f4_t w = ((const f4_t*)src)[r];
    h4_t h = {(_Float16)(w[0]*s), (_Float16)(w[1]*s),
              (_Float16)(w[2]*s), (_Float16)(w[3]*s)};
    ((h4_t*)Wh)[i] = h;
}

// ---------------------------------------------------------------------------
// Kernel 1: QKV projection (R14 best config).  One block = (b, n-tile, mat),
//   2 waves.  Stage x tile -> LDS f16 (coalesced reads), then wave w computes
//   output-channel half w*96 via ds_read B-fragments.  1728 blocks x 128 thr,
//   __launch_bounds__(128,4) -> 8 blocks/CU = 2048 slots -> single round.
//   (R15's LDS-free xT variant regressed: per-lane 384B-stride loads are
//   uncoalesced, and the extra xconv kernel cost ~5 us.)
// ---------------------------------------------------------------------------
__global__ __launch_bounds__(128, 4) void proj_kernel(
    const float* __restrict__ x, const _Float16* __restrict__ Wh,
    const float* __restrict__ bq, const float* __restrict__ bk,
    const float* __restrict__ bv,
    _Float16* __restrict__ QT, _Float16* __restrict__ KT, _Float16* __restrict__ Vg)
{
    __shared__ __align__(16) _Float16 Xs[32 * 200];   // [n][c], 200-hw row stride

    const int tid  = threadIdx.x;                 // 0..127
    const int lane = tid & 63, wave = tid >> 6;   // wave 0..1
    const int L31  = lane & 31, hi = lane >> 5;
    const int bid  = blockIdx.x;                  // (b*288 + ntile)*3 + mat
    const int mat  = bid % 3;
    const int bt   = bid / 3;
    const int b    = bt / 288;
    const int n0   = (bt % 288) * 32;

    // stage x[b, :, n0:n0+32] -> Xs: thread (nn=tid&31, c0=(tid>>5)*48)
    {
        const int nn = tid & 31;
        const int c0 = (tid >> 5) * 48;           // 0,48,96,144
        const float* xp = x + (size_t)(b * CDIM + c0) * NSEQ + n0 + nn;
        #pragma unroll
        for (int g = 0; g < 12; g++) {
            h4_t h = {(_Float16)xp[(size_t)(4*g+0) * NSEQ],
                      (_Float16)xp[(size_t)(4*g+1) * NSEQ],
                      (_Float16)xp[(size_t)(4*g+2) * NSEQ],
                      (_Float16)xp[(size_t)(4*g+3) * NSEQ]};
            *(h4_t*)(Xs + nn * 200 + c0 + 4 * g) = h;
        }
    }
    __syncthreads();

    const int sh = wave * 3;             // wave 0: ch 0-95, wave 1: ch 96-191
    const int n  = n0 + L31;

    h8_t bf[12];
    #pragma unroll
    for (int t = 0; t < 12; t++)
        bf[t] = *(const h8_t*)(Xs + L31 * 200 + t * 16 + hi * 8);

    const _Float16* W = Wh + mat * CDIM * CDIM;
    const float* bias = (mat == 0) ? bq : (mat == 1 ? bk : bv);
    const float bscale = (mat == 0) ? LOG2E : 1.f;

    f16v acc[3];
    #pragma unroll
    for (int s = 0; s < 3; s++)
        #pragma unroll
        for (int r = 0; r < 16; r++) acc[s][r] = 0.f;

    #pragma unroll
    for (int t = 0; t < 12; t++) {
        #pragma unroll
        for (int s = 0; s < 3; s++) {
            h8_t a = *(const h8_t*)(W + ((sh + s) * 32 + L31) * CDIM + t * 16 + hi * 8);
            acc[s] = __builtin_amdgcn_mfma_f32_32x32x16_f16(a, bf[t], acc[s], 0, 0, 0);
        }
    }

    if (mat < 2) {
        _Float16* dst = ((mat == 0) ? QT : KT) + ((size_t)b * NSEQ + n) * CDIM;
        #pragma unroll
        for (int s = 0; s < 3; s++) {
            #pragma unroll
            for (int g = 0; g < 4; g++) {
                f4_t bb = *(const f4_t*)&bias[(sh + s) * 32 + 8 * g + 4 * hi];
                h4_t h = {(_Float16)(acc[s][4*g+0] + bb[0] * bscale),
                          (_Float16)(acc[s][4*g+1] + bb[1] * bscale),
                          (_Float16)(acc[s][4*g+2] + bb[2] * bscale),
                          (_Float16)(acc[s][4*g+3] + bb[3] * bscale)};
                *(h4_t*)(dst + (sh + s) * 32 + 8 * g + 4 * hi) = h;
            }
        }
    } else {
        #pragma unroll
        for (int s = 0; s < 3; s++) {
            #pragma unroll
            for (int g = 0; g < 4; g++) {
                f4_t bb = *(const f4_t*)&bias[(sh + s) * 32 + 8 * g + 4 * hi];
                #pragma unroll
                for (int r = 0; r < 4; r++) {
                    int o = (sh + s) * 32 + 8 * g + 4 * hi + r;
                    Vg[((size_t)b * CDIM + o) * NSEQ + n] =
                        (_Float16)(acc[s][4*g+r] + bb[r]);
                }
            }
        }
    }
}

// ---------------------------------------------------------------------------
// Kernel 2: flash attention (R9 exact -- best measured, ~165 us).
//   Full global_load_lds DMA staging, double-buffered K and V, ONE
//   __syncthreads per iter, source-side swizzle for conflict-free reads:
//   K chunk rotate (key&7) mod 24, V seg rotate (c>>1)&3.
//   K bufs at 0/12288, V bufs at 24576/36864.  NSPLIT=7 -> 1008 blocks
//   ~ 2 full rounds at 2 blocks/CU (98.4% slot efficiency).
//   Nulls (reverted): chain-split, counted-vmcnt triple-buf, T15 pipeline,
//   setprio, hybrid staging, xconv/LDS-free proj.
// ---------------------------------------------------------------------------
template<int NSPLIT>
__global__ __launch_bounds__(256, 2) void flash_kernel(
    const _Float16* __restrict__ QT, const _Float16* __restrict__ KTg,
    const _Float16* __restrict__ Vg,
    _Float16* __restrict__ O_part, float* __restrict__ m_part, float* __restrict__ l_part)
{
    constexpr int TKI  = NSEQ / 32;               // 288 total k-iters
    constexpr int base = TKI / NSPLIT, rem = TKI % NSPLIT;
    __shared__ __align__(16) _Float16 Sh[25600];  // 51,200 B

    const int tid  = threadIdx.x;
    const int lane = tid & 63, wave = tid >> 6;
    const int L31  = lane & 31, hi = lane >> 5;
    const int qtile = blockIdx.x, split = blockIdx.y, b = blockIdx.z;
    const int q0 = qtile * 128 + wave * 32;

    const int nk     = base + (split < rem ? 1 : 0);
    const int kstart = split * base + (split < rem ? split : rem);

    // resident Q B-fragments: B[k=c][col=q=L31]
    h8_t qf[12];
    const _Float16* qbase = QT + ((size_t)b * NSEQ + q0 + L31) * CDIM + hi * 8;
    #pragma unroll
    for (int t = 0; t < 12; t++) qf[t] = *(const h8_t*)(qbase + t * 16);

    f16v acc[6];
    #pragma unroll
    for (int s = 0; s < 6; s++)
        #pragma unroll
        for (int r = 0; r < 16; r++) acc[s][r] = 0.f;
    float m_run = -__builtin_inff();
    float l_run = 0.f;

    const _Float16* ksrc = KTg + ((size_t)b * NSEQ + kstart * 32) * CDIM;
    const _Float16* vsrc = Vg + (size_t)b * CDIM * NSEQ + kstart * 32;

    // ---- read-side offsets (loop-invariant, buffer chosen by imm) ----
    const int k7 = L31 & 7;
    int ka[12];                                   // byte offsets in K buffer
    #pragma unroll
    for (int t = 0; t < 12; t++) {
        int p = 2 * t + hi + k7; if (p >= 24) p -= 24;
        ka[t] = L31 * 384 + p * 16;
    }
    const int r2 = L31 >> 1;
    const int va0 = L31 * 64 + (((hi + r2) & 3) * 16);       // ks=0
    const int va1 = L31 * 64 + (((2 + hi + r2) & 3) * 16);   // ks=1

    // ---- stage-side per-lane global pointers (source-swizzled) ----
    const _Float16 *kp[3], *vp[3];
    #pragma unroll
    for (int r = 0; r < 3; r++) {
        int i = r * 256 + tid;                    // linear 16B-chunk index
        int row = i / 24, pp = i % 24;
        int c = pp - (row & 7); if (c < 0) c += 24;
        kp[r] = ksrc + row * CDIM + c * 8;
        int cv = i >> 2, s = i & 3;
        int g = (s - (cv >> 1)) & 3;
        vp[r] = vsrc + (size_t)cv * NSEQ + g * 8;
    }

    auto stage = [&](int kbB, int vbB) {          // DMA tile at kp/vp, advance
        #pragma unroll
        for (int r = 0; r < 3; r++) {
            int off = (r * 256 + wave * 64) * 16;
            gl_lds16(kp[r], (_Float16*)((char*)Sh + kbB + off));
            gl_lds16(vp[r], (_Float16*)((char*)Sh + vbB + off));
        }
        #pragma unroll
        for (int r = 0; r < 3; r++) { kp[r] += 32 * CDIM; vp[r] += 32; }
    };

    stage(0, 24576);                              // tile 0 -> buffer 0
    __syncthreads();                              // (drains vmcnt)

    auto body = [&](int kt, int KB, int VB, int KW, int VW) {
        if (kt + 1 < nk) stage(KW, VW);           // next tile -> other buffer

        // S^T[key][q]: A = K[key=L31][c] from K buf, B = qf
        f16v st;
        #pragma unroll
        for (int r = 0; r < 16; r++) st[r] = 0.f;
        #pragma unroll
        for (int t = 0; t < 12; t++) {
            h8_t a = *(const h8_t*)((char*)Sh + KB + ka[t]);
            st = __builtin_amdgcn_mfma_f32_32x32x16_f16(a, qf[t], st, 0, 0, 0);
        }

        // tile max tree, cross-half combine via permlane
        float a0 = fmaxf(fmaxf(st[0], st[1]),  st[2]);
        float a1 = fmaxf(fmaxf(st[3], st[4]),  st[5]);
        float a2 = fmaxf(fmaxf(st[6], st[7]),  st[8]);
        float a3 = fmaxf(fmaxf(st[9], st[10]), st[11]);
        float a4 = fmaxf(fmaxf(st[12], st[13]), st[14]);
        float mx = fmaxf(fmaxf(fmaxf(a0, a1), fmaxf(a2, a3)), fmaxf(a4, st[15]));
        u32x2 mxw = plswap(f2u(mx), f2u(mx));
        mx = fmaxf(u2f(mxw[0]), u2f(mxw[1]));

        // defer-max rescale (rare after iter 0)
        if (__builtin_expect(__any(mx > m_run + 9.f), 0)) {
            float m_new = fmaxf(m_run, mx);
            float alpha = __builtin_exp2f(m_run - m_new);
            l_run *= alpha;
            #pragma unroll
            for (int cs = 0; cs < 6; cs++)
                #pragma unroll
                for (int r = 0; r < 16; r++) acc[cs][r] *= alpha;
            m_run = m_new;
        }

        // P = exp2(S - m_run), pack f16 pairs
        unsigned pu[8];
        float ps0 = 0.f, ps1 = 0.f;
        #pragma unroll
        for (int t2 = 0; t2 < 8; t2++) {
            float e0 = __builtin_exp2f(st[2*t2]   - m_run);
            float e1 = __builtin_exp2f(st[2*t2+1] - m_run);
            ps0 += e0; ps1 += e1;
            pu[t2] = cvt_pk(e0, e1);
        }
        l_run += ps0 + ps1;

        // half-exchange via permlane32_swap
        union { h8_t h; unsigned u[4]; } pb0, pb1;
        u32x2 x0 = plswap(pu[0], pu[2]);
        u32x2 x1 = plswap(pu[1], pu[3]);
        u32x2 x2 = plswap(pu[4], pu[6]);
        u32x2 x3 = plswap(pu[5], pu[7]);
        pb0.u[0] = x0[0]; pb0.u[1] = x1[0]; pb0.u[2] = x0[1]; pb0.u[3] = x1[1];
        pb1.u[0] = x2[0]; pb1.u[1] = x3[0]; pb1.u[2] = x2[1]; pb1.u[3] = x3[1];

        // PV flipped: D[m=c][n=q] += V[c][key] * P^T[key][q]
        #pragma unroll
        for (int ks = 0; ks < 2; ks++) {
            h8_t pb = ks ? pb1.h : pb0.h;
            int vaof = ks ? va1 : va0;
            #pragma unroll
            for (int cs = 0; cs < 6; cs++) {
                h8_t va = *(const h8_t*)((char*)Sh + VB + cs * 2048 + vaof);
                acc[cs] = __builtin_amdgcn_mfma_f32_32x32x16_f16(va, pb, acc[cs], 0, 0, 0);
            }
        }

        __syncthreads();   // single convergence point (drains this wave's DMA)
    };

    int kt = 0;
    for (; kt + 1 < nk; kt += 2) {
        body(kt,     0,     24576, 12288, 36864);
        body(kt + 1, 12288, 36864, 0,     24576);
    }
    if (kt < nk)                                   // odd split size tail
        body(kt, 0, 24576, 12288, 36864);

    // epilogue
    u32x2 lw = plswap(f2u(l_run), f2u(l_run));
    float l_tot = u2f(lw[0]) + u2f(lw[1]);
    const size_t pw = (size_t)(b * NSPLIT + split) * NSEQ + q0;
    if (lane < 32) {
        m_part[pw + lane] = m_run;
        l_part[pw + lane] = l_tot;
    }
    // per-wave transpose through LDS (loop-end barrier separates last reads)
    _Float16* T = Sh + wave * 6400;
    #pragma unroll
    for (int cs = 0; cs < 6; cs++)
        #pragma unroll
        for (int g = 0; g < 4; g++) {
            h4_t hh = {(_Float16)acc[cs][4*g+0], (_Float16)acc[cs][4*g+1],
                       (_Float16)acc[cs][4*g+2], (_Float16)acc[cs][4*g+3]};
            *(h4_t*)(T + L31 * 200 + cs * 32 + 8 * g + 4 * hi) = hh;
        }
    _Float16* ob = O_part + pw * CDIM;
    #pragma unroll
    for (int it = 0; it < 12; it++) {
        int i = it * 64 + lane;
        int qq = i / 24, col = i % 24;
        h8_t h = *(const h8_t*)(T + qq * 200 + col * 8);
        *(h8_t*)(ob + (size_t)qq * CDIM + col * 8) = h;
    }
}

// ---------------------------------------------------------------------------
// Kernel 3: merge NS splits, normalize (log2 domain), transpose to out[b][c][n]
// ---------------------------------------------------------------------------
template<int NS>
__global__ __launch_bounds__(256) void combine_kernel(
    const _Float16* __restrict__ O_part, const float* __restrict__ m_part,
    const float* __restrict__ l_part, float* __restrict__ out)
{
    __shared__ float Cs[CDIM][33];
    __shared__ float winv[NS][32];
    const int tid = threadIdx.x;
    const int b  = blockIdx.y;
    const int n0 = blockIdx.x * 32;

    if (tid < 32) {
        int n = n0 + tid;
        float mm[NS], ll[NS], ms = -__builtin_inff();
        #pragma unroll
        for (int s = 0; s < NS; s++) {
            mm[s] = m_part[(b * NS + s) * NSEQ + n];
            ll[s] = l_part[(b * NS + s) * NSEQ + n];
            ms = fmaxf(ms, mm[s]);
        }
        float denom = 0.f;
        #pragma unroll
        for (int s = 0; s < NS; s++) {
            float w = __builtin_exp2f(mm[s] - ms);
            mm[s] = w;
            denom += w * ll[s];
        }
        #pragma unroll
        for (int s = 0; s < NS; s++) winv[s][tid] = mm[s] / denom;
    }
    __syncthreads();

    for (int i = tid; i < 32 * 24; i += 256) {
        int nl = i / 24, cp = i % 24;          // cp: group of 8 channels
        float v[8];
        #pragma unroll
        for (int j = 0; j < 8; j++) v[j] = 0.f;
        #pragma unroll
        for (int s = 0; s < NS; s++) {
            h8_t op = *(const h8_t*)(O_part +
                ((size_t)(b * NS + s) * NSEQ + n0 + nl) * CDIM + cp * 8);
            float w = winv[s][nl];
            #pragma unroll
            for (int j = 0; j < 8; j++) v[j] += w * (float)op[j];
        }
        #pragma unroll
        for (int j = 0; j < 8; j++) Cs[cp * 8 + j][nl] = v[j];
    }
    __syncthreads();
    for (int i = tid; i < CDIM * 32; i += 256) {
        int nl = i & 31, c = i >> 5;
        out[((size_t)b * CDIM + c) * NSEQ + n0 + nl] = Cs[c][nl];
    }
}

// ---------------------------------------------------------------------------
extern "C" void kernel_launch(void* const* d_in, const int* in_sizes, int n_in,
                              void* d_out, int out_size, void* d_ws, size_t ws_size,
                              hipStream_t stream)
{
    const float* x  = (const float*)d_in[0];
    const float* Wq = (const float*)d_in[1];
    const float* bq = (const float*)d_in[2];
    const float* Wk = (const float*)d_in[3];
    const float* bk = (const float*)d_in[4];
    const float* Wv = (const float*)d_in[5];
    const float* bv = (const float*)d_in[6];
    float* out = (float*)d_out;

    // workspace layout
    char* ws = (char*)d_ws;
    _Float16* QT = (_Float16*)(ws);                    // 7,077,888 B
    _Float16* KT = (_Float16*)(ws + 7077888);
    _Float16* Vg = (_Float16*)(ws + 14155776);
    char* tail = ws + 21233664;
    _Float16* Wh = (_Float16*)tail;                    // 221,184 B, aliases O_part
    _Float16* O_part = (_Float16*)tail;                // NS * 7,077,888 B (f16)

    wconv_kernel<<<108, 256, 0, stream>>>(Wq, Wk, Wv, Wh);
    proj_kernel<<<1728, 128, 0, stream>>>(x, Wh, bq, bk, bv, QT, KT, Vg);

    const size_t need7 = 21233664ull + 7 * 7077888ull + 2 * 516096ull;  // 71,811,072
    const size_t need4 = 21233664ull + 4 * 7077888ull + 2 * 294912ull;  // 50,135,040
    if (ws_size >= need7) {
        float* m_part = (float*)(tail + 7 * 7077888ull);
        float* l_part = (float*)(tail + 7 * 7077888ull + 516096ull);
        flash_kernel<7><<<dim3(72, 7, 2), 256, 0, stream>>>(QT, KT, Vg, O_part, m_part, l_part);
        combine_kernel<7><<<dim3(288, 2), 256, 0, stream>>>(O_part, m_part, l_part, out);
    } else if (ws_size >= need4) {
        float* m_part = (float*)(tail + 4 * 7077888ull);
        float* l_part = (float*)(tail + 4 * 7077888ull + 294912ull);
        flash_kernel<4><<<dim3(72, 4, 2), 256, 0, stream>>>(QT, KT, Vg, O_part, m_part, l_part);
        combine_kernel<4><<<dim3(288, 2), 256, 0, stream>>>(O_part, m_part, l_part, out);
    } else {
        float* m_part = (float*)(tail + 2 * 7077888ull);
        float* l_part = (float*)(tail + 2 * 7077888ull + 147456ull);
        flash_kernel<2><<<dim3(72, 2, 2), 256, 0, stream>>>(QT, KT, Vg, O_part, m_part, l_part);
        combine_kernel<2><<<dim3(288, 2), 256, 0, stream>>>(O_part, m_part, l_part, out);
    }
}